// Round 9
// baseline (66.846 us; speedup 1.0000x reference)
//
#include <hip/hip_runtime.h>

#define D      64
#define K      512
#define Q_OFF  0            // out[0 .. 8388607]   quantized_ste (NCHW)
#define L_OFF  8388608      // out[8388608]        commitment loss
#define I_OFF  8388609      // out[8388609 .. ]    indices (131072)

// ws layout (floats)
#define WS_ET    0          // 512*64 transposed embeddings (fp32, exact)
#define WS_EN    32768      // 512 ||e||^2
#define WS_ENH   33280      // 512 0.5*||e||^2
#define WS_PART  33792      // partial loss sums

// B-fragment tables staged in out[] (quantized region, rewritten later)
#define B_LO_OFF 4096

// packed fixed-point selection constants
#define SEL_SCALE 16384.0f              // 2^14: resolution 6.1e-5
#define SEL_BIAS  (160.0f * 16384.0f)   // acc in (-160, 256) -> positive

typedef __attribute__((ext_vector_type(8))) short short8;   // 8 bf16 = 4 VGPRs
typedef __attribute__((ext_vector_type(4))) float f32x4;

static __device__ __forceinline__ unsigned short f2bf(float f) {
    unsigned u = __float_as_uint(f);
    u += 0x7fffu + ((u >> 16) & 1u);       // RTN-even
    return (unsigned short)(u >> 16);
}
static __device__ __forceinline__ float bf2f(unsigned short h) {
    return __uint_as_float(((unsigned)h) << 16);
}

// async global->LDS, 16 B per lane, linear layout (lds dest: wave base + lane*16)
__device__ __forceinline__ void gload_lds16(const float* g, float* l) {
    __builtin_amdgcn_global_load_lds(
        (const __attribute__((address_space(1))) unsigned int*)g,
        (__attribute__((address_space(3))) unsigned int*)l, 16, 0, 0);
}

// ---------------------------------------------------------------- prep ----
__global__ __launch_bounds__(256) void vq_prep(const float* __restrict__ E,
                                               float* __restrict__ ws,
                                               float* __restrict__ out) {
    int g = blockIdx.x * 256 + threadIdx.x;   // 0..2047 = (t, lane)
    int t = g >> 6, lane = g & 63;
    int col = lane & 15, kg = lane >> 4;
    int code = t * 16 + col;
    short8* bhp = (short8*)out;               // 64 KB
    short8* blp = (short8*)out + B_LO_OFF;    // next 64 KB
#pragma unroll
    for (int s = 0; s < 2; ++s) {
        short8 h, l;
#pragma unroll
        for (int j = 0; j < 8; ++j) {
            int k = s * 32 + kg * 8 + j;
            float v = -E[k * K + code];
            unsigned short hb = f2bf(v);
            h[j] = (short)hb;
            l[j] = (short)f2bf(v - bf2f(hb));
        }
        bhp[(t * 2 + s) * 64 + lane] = h;
        blp[(t * 2 + s) * 64 + lane] = l;
    }
    if (g < K) {
        float nsq = 0.f;
#pragma unroll 8
        for (int d = 0; d < D; ++d) {
            float v = E[d * K + g];
            ws[WS_ET + g * D + d] = v;
            nsq = fmaf(v, v, nsq);
        }
        ws[WS_EN + g]  = nsq;
        ws[WS_ENH + g] = 0.5f * nsq;
    }
}

// ---------------------------------------------------------------- dist ----
// 2048 blocks x 2 waves; wave owns 32 pixels (2 M-tiles) x 512 codes.
// 8 independent barrier-groups per CU -> destaggered phases keep the matrix
// pipe fed. B-fragments chunk-staged (2 code-tiles = 8 KB) into double-
// buffered LDS via global_load_lds; enh staged to LDS once. Packed
// fixed-point top-2 selection (first-min-wins = np.argmin semantics).
__global__ __launch_bounds__(128, 4) void vq_dist(const float* __restrict__ x,
                                                  const float* __restrict__ ws,
                                                  float* __restrict__ out) {
    __shared__ float sbuf[2][2048];           // 2 x 8 KB: hi [0,1024), lo [1024,2048)
    __shared__ float senh[512];               // 0.5*||e||^2 table

    const int tid = threadIdx.x, w = tid >> 6, lane = tid & 63;
    const int col = lane & 15, rowg = lane >> 4;
    const int pixw = blockIdx.x * 64 + w * 32;

    const float* bh  = (const float*)out;                  // hi table
    const float* bl  = (const float*)out + B_LO_OFF * 4;   // lo table

    // stage chunk 0 (tiles 0,1) + enh table
    {
        float* db = sbuf[0];
#pragma unroll
        for (int q = 0; q < 2; ++q) {
            gload_lds16(bh + q * 512 + tid * 4, db + q * 512 + tid * 4);
            gload_lds16(bl + q * 512 + tid * 4, db + 1024 + q * 512 + tid * 4);
        }
        gload_lds16(ws + WS_ENH + tid * 4, senh + tid * 4);
    }

    // ---- load x fragments and split to bf16 hi/lo: A[mt][s]
    short8 ah[2][2], al[2][2];
#pragma unroll
    for (int mt = 0; mt < 2; ++mt) {
        int pix = pixw + mt * 16 + col;
        const float* xp = x + ((size_t)(pix >> 12) << 18) + (pix & 4095);
#pragma unroll
        for (int s = 0; s < 2; ++s) {
            short8 h, l;
#pragma unroll
            for (int j = 0; j < 8; ++j) {
                float v = xp[(size_t)(s * 32 + rowg * 8 + j) << 12];
                unsigned short hb = f2bf(v);
                h[j] = (short)hb;
                l[j] = (short)f2bf(v - bf2f(hb));
            }
            ah[mt][s] = h; al[mt][s] = l;
        }
    }

    unsigned m1[2][4], m2[2][4];
#pragma unroll
    for (int mt = 0; mt < 2; ++mt)
#pragma unroll
        for (int r = 0; r < 4; ++r) { m1[mt][r] = 0xFFFFFFFFu; m2[mt][r] = 0xFFFFFFFFu; }

    __syncthreads();                           // chunk 0 + enh staged

#pragma unroll 2
    for (int c = 0; c < 16; ++c) {
        // prefetch chunk c+1 into the other buffer
        if (c + 1 < 16) {
            const float* sh = bh + (c + 1) * 1024;
            const float* sl = bl + (c + 1) * 1024;
            float* db = sbuf[(c + 1) & 1];
#pragma unroll
            for (int q = 0; q < 2; ++q) {
                gload_lds16(sh + q * 512 + tid * 4, db + q * 512 + tid * 4);
                gload_lds16(sl + q * 512 + tid * 4, db + 1024 + q * 512 + tid * 4);
            }
        }

        const short8* sb = (const short8*)sbuf[c & 1];
#pragma unroll
        for (int p = 0; p < 2; ++p) {
            const int t = c * 2 + p;
            const float ev = senh[t * 16 + col];
            const unsigned codev = (unsigned)(t * 16 + col);

            short8 cbh0 = sb[p * 128 + lane];
            short8 cbh1 = sb[p * 128 + 64 + lane];
            short8 cbl0 = sb[256 + p * 128 + lane];
            short8 cbl1 = sb[256 + p * 128 + 64 + lane];

            f32x4 acc0 = { ev, ev, ev, ev };
            f32x4 acc1 = { ev, ev, ev, ev };
            __builtin_amdgcn_s_setprio(1);
            acc0 = __builtin_amdgcn_mfma_f32_16x16x32_bf16(ah[0][0], cbh0, acc0, 0, 0, 0);
            acc0 = __builtin_amdgcn_mfma_f32_16x16x32_bf16(al[0][0], cbh0, acc0, 0, 0, 0);
            acc0 = __builtin_amdgcn_mfma_f32_16x16x32_bf16(ah[0][0], cbl0, acc0, 0, 0, 0);
            acc0 = __builtin_amdgcn_mfma_f32_16x16x32_bf16(ah[0][1], cbh1, acc0, 0, 0, 0);
            acc0 = __builtin_amdgcn_mfma_f32_16x16x32_bf16(al[0][1], cbh1, acc0, 0, 0, 0);
            acc0 = __builtin_amdgcn_mfma_f32_16x16x32_bf16(ah[0][1], cbl1, acc0, 0, 0, 0);
            acc1 = __builtin_amdgcn_mfma_f32_16x16x32_bf16(ah[1][0], cbh0, acc1, 0, 0, 0);
            acc1 = __builtin_amdgcn_mfma_f32_16x16x32_bf16(al[1][0], cbh0, acc1, 0, 0, 0);
            acc1 = __builtin_amdgcn_mfma_f32_16x16x32_bf16(ah[1][0], cbl0, acc1, 0, 0, 0);
            acc1 = __builtin_amdgcn_mfma_f32_16x16x32_bf16(ah[1][1], cbh1, acc1, 0, 0, 0);
            acc1 = __builtin_amdgcn_mfma_f32_16x16x32_bf16(al[1][1], cbh1, acc1, 0, 0, 0);
            acc1 = __builtin_amdgcn_mfma_f32_16x16x32_bf16(ah[1][1], cbl1, acc1, 0, 0, 0);
            __builtin_amdgcn_s_setprio(0);

            // packed top-2 update: 6 VALU per acc element
#pragma unroll
            for (int r = 0; r < 4; ++r) {
                unsigned u0 = (unsigned)fmaf(acc0[r], SEL_SCALE, SEL_BIAS);
                unsigned p0 = (u0 << 9) + codev;
                m2[0][r] = min(m2[0][r], max(m1[0][r], p0));
                m1[0][r] = min(m1[0][r], p0);
                unsigned u1 = (unsigned)fmaf(acc1[r], SEL_SCALE, SEL_BIAS);
                unsigned p1 = (u1 << 9) + codev;
                m2[1][r] = min(m2[1][r], max(m1[1][r], p1));
                m1[1][r] = min(m1[1][r], p1);
            }
        }
        __syncthreads();   // stage c+1 landed; both waves done with buf (c&1)
    }

    // cross-lane top-2 merge over the 16 code-columns, write packed (c1|c2<<16)
    unsigned* outu = (unsigned*)out;
#pragma unroll
    for (int mt = 0; mt < 2; ++mt)
#pragma unroll
        for (int r = 0; r < 4; ++r) {
            unsigned v1 = m1[mt][r], v2 = m2[mt][r];
#pragma unroll
            for (int m = 1; m < 16; m <<= 1) {
                unsigned o1 = (unsigned)__shfl_xor((int)v1, m, 16);
                unsigned o2 = (unsigned)__shfl_xor((int)v2, m, 16);
                v2 = min(max(v1, o1), min(v2, o2));
                v1 = min(v1, o1);
            }
            if (col == r) {
                int p = pixw + mt * 16 + rowg * 4 + r;
                unsigned c1 = v1 & 511u, c2 = v2 & 511u;
                outu[I_OFF + p] = c1 | (c2 << 16);
            }
        }
}

// ----------------------------------------------------------------- out ----
__device__ __forceinline__ float dotrow(const float* __restrict__ er,
                                        const float* __restrict__ xv) {
    const float4* e4 = (const float4*)er;
    float a0 = 0.f, a1 = 0.f, a2 = 0.f, a3 = 0.f;
#pragma unroll
    for (int q = 0; q < 16; ++q) {
        float4 e = e4[q];
        a0 = fmaf(xv[4*q+0], e.x, a0);
        a1 = fmaf(xv[4*q+1], e.y, a1);
        a2 = fmaf(xv[4*q+2], e.z, a2);
        a3 = fmaf(xv[4*q+3], e.w, a3);
    }
    return (a0 + a1) + (a2 + a3);
}

__global__ __launch_bounds__(256) void vq_out(const float* __restrict__ x,
                                              const float* __restrict__ ws,
                                              float* __restrict__ out,
                                              float* __restrict__ partial) {
    const float* ET = ws + WS_ET;
    const float* EN = ws + WS_EN;
    int n  = blockIdx.x * 256 + threadIdx.x;
    int b  = n >> 12;
    int hw = n & 4095;

    const float* xp = x + ((size_t)b << 18) + hw;
    float xv[D];
#pragma unroll
    for (int d = 0; d < D; ++d) xv[d] = xp[(size_t)d << 12];

    unsigned packed = ((const unsigned*)out)[I_OFF + n];
    int c1 = (int)(packed & 0xffffu), c2 = (int)(packed >> 16);

    float d1 = fmaf(-2.f, dotrow(ET + (c1 << 6), xv), EN[c1]);
    float d2 = fmaf(-2.f, dotrow(ET + (c2 << 6), xv), EN[c2]);
    bool sw = (d2 < d1) || (d2 == d1 && c2 < c1);   // np.argmin: first min wins
    int bestk = sw ? c2 : c1;

    out[I_OFF + n] = (float)bestk;

    const float* qv = ET + (bestk << 6);
    float* op = out + Q_OFF + ((size_t)b << 18) + hw;
    float lsum = 0.f;
#pragma unroll
    for (int d = 0; d < D; ++d) {
        float qd = qv[d];
        op[(size_t)d << 12] = qd;
        float diff = xv[d] - qd;
        lsum = fmaf(diff, diff, lsum);
    }

#pragma unroll
    for (int off = 32; off > 0; off >>= 1)
        lsum += __shfl_down(lsum, off, 64);
    __shared__ float wsum[4];
    if ((threadIdx.x & 63) == 0) wsum[threadIdx.x >> 6] = lsum;
    __syncthreads();
    if (threadIdx.x == 0)
        partial[blockIdx.x] = (wsum[0] + wsum[1]) + (wsum[2] + wsum[3]);
}

__global__ __launch_bounds__(256) void vq_final(const float* __restrict__ partial,
                                                float* __restrict__ out) {
    int t = threadIdx.x;
    float s = partial[t] + partial[t + 256];
#pragma unroll
    for (int off = 32; off > 0; off >>= 1)
        s += __shfl_down(s, off, 64);
    __shared__ float wsum[4];
    if ((t & 63) == 0) wsum[t >> 6] = s;
    __syncthreads();
    if (t == 0)
        out[L_OFF] = ((wsum[0] + wsum[1]) + (wsum[2] + wsum[3])) * (1.f / 8388608.f);
}

extern "C" void kernel_launch(void* const* d_in, const int* in_sizes, int n_in,
                              void* d_out, int out_size, void* d_ws, size_t ws_size,
                              hipStream_t stream) {
    const float* x = (const float*)d_in[0];
    const float* E = (const float*)d_in[1];
    float* out = (float*)d_out;
    float* ws  = (float*)d_ws;

    hipLaunchKernelGGL(vq_prep,  dim3(8),    dim3(256), 0, stream, E, ws, out);
    hipLaunchKernelGGL(vq_dist,  dim3(2048), dim3(128), 0, stream, x, ws, out);
    hipLaunchKernelGGL(vq_out,   dim3(512),  dim3(256), 0, stream, x, ws, out, ws + WS_PART);
    hipLaunchKernelGGL(vq_final, dim3(1),    dim3(256), 0, stream, ws + WS_PART, out);
}